// Round 1
// baseline (116.675 us; speedup 1.0000x reference)
//
#include <hip/hip_runtime.h>
#include <math.h>

#define DIM 64
#define KHALF 512      // h = -512..511 ; we use k = 1..kmax (pairs with -k), kmax <= 511
#define PMAX 16

// workspace layout (float indices)
#define WS_MAXSS   0                      // uint bits of max sum-of-squares (atomicMax)
#define WS_SF      1                      // float sf = 0.3 / max_norm
#define WS_KMAX    2                      // int kmax
#define WS_KFT     4                      // kft[k-1], k = 1..512
#define WS_ARE     (4 + KHALF)            // a_re[p][k-1], PMAX x 512 (kft folded in)
#define WS_AIM     (WS_ARE + PMAX*KHALF)  // a_im[p][k-1]
#define WS_RPX     (WS_AIM + PMAX*KHALF)  // raw projections x: [p][i] (P*N), then y: [p][j] (P*M)

// ---------------- kernel 1: max row sumsq over x and y ----------------
__global__ void k_maxnorm(const float* __restrict__ x, const float* __restrict__ y,
                          int N, int M, unsigned* __restrict__ ws_bits) {
    int rows = N + M;
    float mx = 0.f;
    for (int r = blockIdx.x * blockDim.x + threadIdx.x; r < rows; r += gridDim.x * blockDim.x) {
        const float4* p = (const float4*)((r < N) ? (x + (size_t)r * DIM)
                                                  : (y + (size_t)(r - N) * DIM));
        float ss = 0.f;
#pragma unroll
        for (int d = 0; d < DIM / 4; ++d) {
            float4 v = p[d];
            ss += v.x * v.x + v.y * v.y + v.z * v.z + v.w * v.w;
        }
        mx = fmaxf(mx, ss);
    }
    for (int off = 32; off; off >>= 1) mx = fmaxf(mx, __shfl_down(mx, off));
    __shared__ float smx[8];
    int wid = threadIdx.x >> 6, lane = threadIdx.x & 63;
    if (lane == 0) smx[wid] = mx;
    __syncthreads();
    if (threadIdx.x == 0) {
        float m = smx[0];
        int nw = blockDim.x >> 6;
        for (int w = 1; w < nw; ++w) m = fmaxf(m, smx[w]);
        atomicMax(ws_bits + WS_MAXSS, __float_as_uint(m));  // m >= 0 -> uint order == float order
    }
}

// ---------------- kernel 2: projections (x|y) @ normalize(xi) ----------------
__global__ void k_proj(const float* __restrict__ x, const float* __restrict__ y,
                       const float* __restrict__ xis, int N, int M, int P,
                       float* __restrict__ wsF) {
    __shared__ __align__(16) float sxi[PMAX * DIM];
    __shared__ float sinv[PMAX];
    int tid = threadIdx.x;
    int tot = P * DIM;
    for (int idx = tid * 4; idx < tot; idx += blockDim.x * 4)
        *(float4*)(sxi + idx) = *(const float4*)(xis + idx);
    __syncthreads();
    if (tid < P) {
        float ss = 0.f;
        for (int d = 0; d < DIM; ++d) { float v = sxi[tid * DIM + d]; ss += v * v; }
        sinv[tid] = 1.0f / sqrtf(ss);
    }
    __syncthreads();
    int r = blockIdx.x * blockDim.x + tid;
    if (r >= N + M) return;
    const float4* rowp = (const float4*)((r < N) ? (x + (size_t)r * DIM)
                                                 : (y + (size_t)(r - N) * DIM));
    float acc[PMAX];
#pragma unroll
    for (int p = 0; p < PMAX; ++p) acc[p] = 0.f;
#pragma unroll
    for (int d4 = 0; d4 < DIM / 4; ++d4) {
        float4 xv = rowp[d4];
        for (int p = 0; p < P; ++p) {
            float4 w = *(const float4*)(sxi + p * DIM + d4 * 4);
            acc[p] = fmaf(xv.x, w.x, fmaf(xv.y, w.y, fmaf(xv.z, w.z, fmaf(xv.w, w.w, acc[p]))));
        }
    }
    float* dstx = wsF + WS_RPX;
    if (r < N) {
        for (int p = 0; p < P; ++p) dstx[(size_t)p * N + r] = acc[p] * sinv[p];
    } else {
        float* dsty = dstx + (size_t)P * N;
        int j = r - N;
        for (int p = 0; p < P; ++p) dsty[(size_t)p * M + j] = acc[p] * sinv[p];
    }
}

// ---------------- kernel 3: kft[k] (k=1..512) + kmax + sf ----------------
__global__ void k_kft(const int* __restrict__ scale_raw, float* __restrict__ wsF) {
    int k = threadIdx.x + 1;  // 1..512
    float maxss = __uint_as_float(((const unsigned*)wsF)[WS_MAXSS]);
    float sf = 0.3f / sqrtf(maxss);
    int iv = *scale_raw;
    // scalar could be int32 or float32 bit pattern; disambiguate (10 as float = 0x41200000)
    float scale_f = (iv > -1000000 && iv < 1000000) ? (float)iv : __int_as_float(iv);
    float s2 = (scale_f * sf) * (scale_f * sf);
    // log f = 32 ln(pi) - lgamma(32) + 32 ln(2 pi s^2) + 63 ln k - 2 pi^2 s^2 k^2
    const float C0 = 36.63135635f - 78.09222355f;
    float kf = (float)k;
    float lf = C0 + 32.0f * logf(6.2831853071795864f * s2) + 63.0f * logf(kf)
             - 19.739208802178716f * s2 * kf * kf;
    float kft = expf(lf);  // underflows to 0 exactly like the f32 reference
    wsF[WS_KFT + k - 1] = kft;
    int klocal = (kft > 0.f) ? ((k > 511) ? 511 : k) : 0;
    for (int off = 32; off; off >>= 1) klocal = max(klocal, __shfl_down(klocal, off));
    if ((threadIdx.x & 63) == 0) atomicMax((int*)wsF + WS_KMAX, klocal);
    if (threadIdx.x == 0) wsF[WS_SF] = sf;
}

// ---------------- kernel 4: a_re/a_im[p][k] = kft_k * sum_i w_i {cos,sin}(2pi proj_i k) ----------------
#define KREG 16
__global__ void k_aside(const float* __restrict__ xw, int N, int CH, float* __restrict__ wsF) {
    int p = blockIdx.x / CH, c = blockIdx.x % CH;
    float sf = wsF[WS_SF];
    int kmax = ((const int*)wsF)[WS_KMAX];
    const float* rp = wsF + WS_RPX + (size_t)p * N;
    float* are = wsF + WS_ARE + p * KHALF;
    float* aim = wsF + WS_AIM + p * KHALF;
    int tid = threadIdx.x, lane = tid & 63;
    int stride = CH * blockDim.x;
    for (int kb = 0; kb < kmax; kb += KREG) {
        float accRe[KREG], accIm[KREG];
#pragma unroll
        for (int t = 0; t < KREG; ++t) { accRe[t] = 0.f; accIm[t] = 0.f; }
        for (int i = c * blockDim.x + tid; i < N; i += stride) {
            float w = xw[i];
            float proj = sf * rp[i];  // phase in revolutions per unit k
#pragma unroll
            for (int t = 0; t < KREG; ++t) {
                int k = kb + 1 + t;
                if (k <= kmax) {  // wave-uniform
                    float r = proj * (float)k;
                    r -= rintf(r);                         // [-0.5, 0.5] turns
                    float cs = __builtin_amdgcn_cosf(r);   // cos(2*pi*r)
                    float sn = __builtin_amdgcn_sinf(r);   // sin(2*pi*r)
                    accRe[t] = fmaf(w, cs, accRe[t]);
                    accIm[t] = fmaf(w, sn, accIm[t]);
                }
            }
        }
#pragma unroll
        for (int t = 0; t < KREG; ++t) {
            for (int off = 32; off; off >>= 1) {
                accRe[t] += __shfl_down(accRe[t], off);
                accIm[t] += __shfl_down(accIm[t], off);
            }
        }
        if (lane == 0) {
#pragma unroll
            for (int t = 0; t < KREG; ++t) {
                int k = kb + 1 + t;
                if (k <= kmax) {
                    float kf = wsF[WS_KFT + k - 1];
                    atomicAdd(are + k - 1, accRe[t] * kf);
                    atomicAdd(aim + k - 1, accIm[t] * kf);
                }
            }
        }
    }
}

// ---------------- kernel 5: out[j] = (2/P) sum_p sum_{k>=1} cos*a_re + sin*a_im ----------------
__global__ void k_bside(float* __restrict__ out, int N, int M, int P,
                        const float* __restrict__ wsF) {
    __shared__ float sre[KHALF], sim[KHALF];
    float sf = wsF[WS_SF];
    int kmax = ((const int*)wsF)[WS_KMAX];
    const float* rpy = wsF + WS_RPX + (size_t)P * N;
    int j = blockIdx.x * blockDim.x + threadIdx.x;
    int jj = (j < M) ? j : (M - 1);
    float acc = 0.f;
    for (int p = 0; p < P; ++p) {
        __syncthreads();
        for (int idx = threadIdx.x; idx < kmax; idx += blockDim.x) {
            sre[idx] = wsF[WS_ARE + p * KHALF + idx];
            sim[idx] = wsF[WS_AIM + p * KHALF + idx];
        }
        __syncthreads();
        float proj = sf * rpy[(size_t)p * M + jj];
        for (int k = 1; k <= kmax; ++k) {
            float r = proj * (float)k;
            r -= rintf(r);
            acc = fmaf(__builtin_amdgcn_cosf(r), sre[k - 1], acc);
            acc = fmaf(__builtin_amdgcn_sinf(r), sim[k - 1], acc);
        }
    }
    if (j < M) out[j] = acc * (2.0f / (float)P);
}

extern "C" void kernel_launch(void* const* d_in, const int* in_sizes, int n_in,
                              void* d_out, int out_size, void* d_ws, size_t ws_size,
                              hipStream_t stream) {
    const float* x   = (const float*)d_in[0];
    const float* y   = (const float*)d_in[1];
    const float* xw  = (const float*)d_in[2];
    const float* xis = (const float*)d_in[3];
    const int* scale_raw = (const int*)d_in[4];
    int N = in_sizes[0] / DIM;
    int M = in_sizes[1] / DIM;
    int P = in_sizes[3] / DIM;
    float* wsF = (float*)d_ws;

    // zero: maxnorm bits, sf, kmax, kft, a_re/a_im accumulators
    hipMemsetAsync(d_ws, 0, (size_t)WS_RPX * sizeof(float), stream);

    k_maxnorm<<<64, 256, 0, stream>>>(x, y, N, M, (unsigned*)d_ws);
    int nb = (N + M + 255) / 256;
    k_proj<<<nb, 256, 0, stream>>>(x, y, xis, N, M, P, wsF);
    k_kft<<<1, KHALF, 0, stream>>>(scale_raw, wsF);
    const int CH = 4;
    k_aside<<<P * CH, 256, 0, stream>>>(xw, N, CH, wsF);
    k_bside<<<(M + 255) / 256, 256, 0, stream>>>((float*)d_out, N, M, P, wsF);
}

// Round 3
// 98.016 us; speedup vs baseline: 1.1904x; 1.1904x over previous
//
#include <hip/hip_runtime.h>
#include <math.h>

#define DIM   64
#define PMAX  16
#define KMAXA 64          // upper bound on retained frequencies (actual kmax ~11)
#define KREG  16          // register-tile over k
#define NBLKA 64          // blocks for k_prep (64*256 = 16384 = N+M threads)
#define CH    16          // source chunks per slice in k_adj

// workspace float layout
#define WS_BLOCKMAX 0                         // [NBLKA] per-block max sumsq
#define WS_SF       64                        // float sf
#define WS_KMAX     65                        // int kmax (bit-stored)
#define WS_ARE      128                       // [PMAX][KMAXA] kft-folded a_re
#define WS_AIM      (WS_ARE + PMAX*KMAXA)     // [PMAX][KMAXA]
#define WS_RPX      (WS_AIM + PMAX*KMAXA)     // raw proj x: [P][N], then y: [P][M]

// ---------------- kernel 1: max row sumsq + raw projections + zero accumulators ----------------
__global__ void __launch_bounds__(256) k_prep(
    const float* __restrict__ x, const float* __restrict__ y,
    const float* __restrict__ xis, float* __restrict__ wsF,
    int N, int M, int P)
{
    __shared__ __align__(16) float sxi[PMAX * DIM];
    __shared__ float sinv[PMAX];
    __shared__ float sred[4];
    const int tid = threadIdx.x;
    const int gtid = blockIdx.x * blockDim.x + tid;
    const int gsz = gridDim.x * blockDim.x;

    for (int idx = tid * 4; idx < P * DIM; idx += blockDim.x * 4)
        *(float4*)(sxi + idx) = *(const float4*)(xis + idx);
    __syncthreads();
    if (tid < P) {
        float ss = 0.f;
        for (int d = 0; d < DIM; ++d) { float v = sxi[tid * DIM + d]; ss += v * v; }
        sinv[tid] = 1.0f / sqrtf(ss);
    }
    __syncthreads();

    if (gtid < 2 * PMAX * KMAXA) wsF[WS_ARE + gtid] = 0.f;   // zero a_re/a_im

    float mx = 0.f;
    const int rows = N + M;
    for (int r = gtid; r < rows; r += gsz) {
        const float4* rowp = (const float4*)((r < N) ? (x + (size_t)r * DIM)
                                                     : (y + (size_t)(r - N) * DIM));
        float ss = 0.f;
        float acc[PMAX];
#pragma unroll
        for (int p = 0; p < PMAX; ++p) acc[p] = 0.f;
#pragma unroll
        for (int d4 = 0; d4 < DIM / 4; ++d4) {
            float4 v = rowp[d4];
            ss += v.x * v.x + v.y * v.y + v.z * v.z + v.w * v.w;
#pragma unroll
            for (int p = 0; p < PMAX; ++p) {
                float4 w = *(const float4*)(sxi + p * DIM + d4 * 4);
                acc[p] = fmaf(v.x, w.x, fmaf(v.y, w.y, fmaf(v.z, w.z, fmaf(v.w, w.w, acc[p]))));
            }
        }
        mx = fmaxf(mx, ss);
        float* dst = wsF + WS_RPX + ((r < N) ? (size_t)0 : (size_t)P * N);
        int   rr   = (r < N) ? r : r - N;
        int   L    = (r < N) ? N : M;
#pragma unroll
        for (int p = 0; p < PMAX; ++p)
            dst[(size_t)p * L + rr] = acc[p] * sinv[p];     // raw projection (no sf)
    }
    for (int off = 32; off; off >>= 1) mx = fmaxf(mx, __shfl_down(mx, off));
    if ((tid & 63) == 0) sred[tid >> 6] = mx;
    __syncthreads();
    if (tid == 0) {
        float m = fmaxf(fmaxf(sred[0], sred[1]), fmaxf(sred[2], sred[3]));
        wsF[WS_BLOCKMAX + blockIdx.x] = m;
    }
}

// ---------------- kernel 2: sf/kft/kmax (redundant per block) + adjoint NDFT ----------------
__global__ void __launch_bounds__(256) k_adj(
    const float* __restrict__ xw, const int* __restrict__ scale_raw,
    float* __restrict__ wsF, int N, int P)
{
    __shared__ float skft[KMAXA];
    __shared__ float sacc[2 * KMAXA];
    __shared__ int   s_kmax;
    __shared__ float s_sf;
    const int tid = threadIdx.x;
    const int bid = blockIdx.x;

    // sf from 64 block maxes (wave 0)
    float m = (tid < NBLKA) ? wsF[WS_BLOCKMAX + tid] : 0.f;
    for (int off = 32; off; off >>= 1) m = fmaxf(m, __shfl_down(m, off));
    if (tid == 0) { s_sf = 0.3f / sqrtf(m); s_kmax = 0; }
    __syncthreads();
    const float sf = s_sf;

    int iv = *scale_raw;
    float scale_f = (iv > -1000000 && iv < 1000000) ? (float)iv : __int_as_float(iv);
    float s2 = (scale_f * sf) * (scale_f * sf);
    if (tid < KMAXA) {
        int k = tid + 1;
        float kf = (float)k;
        // log f = 32 ln(pi) - lgamma(32) + 32 ln(2 pi s^2) + 63 ln k - 2 pi^2 s^2 k^2
        const float C0 = 36.63135635f - 78.09222355f;
        float lf = C0 + 32.0f * logf(6.2831853071795864f * s2) + 63.0f * logf(kf)
                 - 19.739208802178716f * s2 * kf * kf;
        float kft = expf(lf);                // underflows to 0 exactly like the f32 reference
        skft[tid] = kft;
        if (kft > 0.f) atomicMax(&s_kmax, k);
    }
    for (int i = tid; i < 2 * KMAXA; i += blockDim.x) sacc[i] = 0.f;
    __syncthreads();
    const int kmax = s_kmax;

    const int pp = bid % P;
    const int c  = bid / P;
    const int NCH = gridDim.x / P;
    const float* rp = wsF + WS_RPX + (size_t)pp * N;
    const int chunk = (N + NCH - 1) / NCH;
    const int i0 = c * chunk, i1 = min(N, i0 + chunk);

    for (int kb = 0; kb < kmax; kb += KREG) {
        float accRe[KREG], accIm[KREG];
#pragma unroll
        for (int t = 0; t < KREG; ++t) { accRe[t] = 0.f; accIm[t] = 0.f; }
        for (int i = i0 + tid; i < i1; i += blockDim.x) {
            float w = xw[i];
            float proj = sf * rp[i];          // phase in revolutions per unit k
#pragma unroll
            for (int t = 0; t < KREG; ++t) {
                int k = kb + 1 + t;
                if (k <= kmax) {              // wave-uniform
                    float r = proj * (float)k;
                    r -= rintf(r);            // [-0.5, 0.5] turns
                    accRe[t] = fmaf(w, __builtin_amdgcn_cosf(r), accRe[t]);
                    accIm[t] = fmaf(w, __builtin_amdgcn_sinf(r), accIm[t]);
                }
            }
        }
#pragma unroll
        for (int t = 0; t < KREG; ++t) {
            int k = kb + 1 + t;
            if (k <= kmax) {
                for (int off = 32; off; off >>= 1) {
                    accRe[t] += __shfl_down(accRe[t], off);
                    accIm[t] += __shfl_down(accIm[t], off);
                }
                if ((tid & 63) == 0) {
                    atomicAdd(&sacc[2 * (k - 1)],     accRe[t]);
                    atomicAdd(&sacc[2 * (k - 1) + 1], accIm[t]);
                }
            }
        }
    }
    __syncthreads();
    if (tid < kmax) {
        float kf = skft[tid];
        atomicAdd(wsF + WS_ARE + pp * KMAXA + tid, sacc[2 * tid] * kf);
        atomicAdd(wsF + WS_AIM + pp * KMAXA + tid, sacc[2 * tid + 1] * kf);
    }
    if (bid == 0 && tid == 0) {
        wsF[WS_SF] = sf;
        ((int*)wsF)[WS_KMAX] = kmax;
    }
}

// ---------------- kernel 3: out[j] = (2/P) sum_p sum_{k>=1} cos*a_re + sin*a_im ----------------
__global__ void __launch_bounds__(256) k_fwd(
    float* __restrict__ out, const float* __restrict__ wsF, int N, int M, int P)
{
    __shared__ float sa[2 * PMAX * KMAXA];
    const int tid = threadIdx.x;
    const float sf = wsF[WS_SF];
    const int kmax = ((const int*)wsF)[WS_KMAX];
    for (int i = tid; i < P * kmax; i += blockDim.x) {
        int pp = i / kmax, kk = i % kmax;
        sa[2 * i]     = wsF[WS_ARE + pp * KMAXA + kk];
        sa[2 * i + 1] = wsF[WS_AIM + pp * KMAXA + kk];
    }
    __syncthreads();
    const float* rpy = wsF + WS_RPX + (size_t)P * N;
    const float invP2 = 2.0f / (float)P;
    for (int j = blockIdx.x * blockDim.x + tid; j < M; j += gridDim.x * blockDim.x) {
        float acc = 0.f;
        for (int pp = 0; pp < P; ++pp) {
            float proj = sf * rpy[(size_t)pp * M + j];
            const float* ap = sa + 2 * pp * kmax;
            for (int kk = 0; kk < kmax; ++kk) {
                float r = proj * (float)(kk + 1);
                r -= rintf(r);
                acc = fmaf(__builtin_amdgcn_cosf(r), ap[2 * kk], acc);
                acc = fmaf(__builtin_amdgcn_sinf(r), ap[2 * kk + 1], acc);
            }
        }
        out[j] = acc * invP2;
    }
}

extern "C" void kernel_launch(void* const* d_in, const int* in_sizes, int n_in,
                              void* d_out, int out_size, void* d_ws, size_t ws_size,
                              hipStream_t stream) {
    const float* x   = (const float*)d_in[0];
    const float* y   = (const float*)d_in[1];
    const float* xw  = (const float*)d_in[2];
    const float* xis = (const float*)d_in[3];
    const int* scale_raw = (const int*)d_in[4];
    float* wsF = (float*)d_ws;
    int N = in_sizes[0] / DIM;
    int M = in_sizes[1] / DIM;
    int P = in_sizes[3] / DIM;

    k_prep<<<NBLKA, 256, 0, stream>>>(x, y, xis, wsF, N, M, P);
    k_adj<<<P * CH, 256, 0, stream>>>(xw, scale_raw, wsF, N, P);
    k_fwd<<<(M + 255) / 256, 256, 0, stream>>>((float*)d_out, wsF, N, M, P);
}